// Round 4
// baseline (206.584 us; speedup 1.0000x reference)
//
#include <hip/hip_runtime.h>
#include <math.h>

#define NN   512
#define NV   8
#define CH   32      // receivers per chunk
#define NCHH 8       // chunks per half-block (2 blocks per sender)

#define C1 0.06154574548966636f   // 1/sqrt(264)
#define C2 0.08838834764831845f   // 1/sqrt(128)
#define SQRT3 1.7320508075688772f

typedef __attribute__((ext_vector_type(8))) short bf16x8;   // 8 bf16 = 4 VGPRs
typedef __attribute__((ext_vector_type(4))) float f32x4;

#define MFMA16 __builtin_amdgcn_mfma_f32_16x16x32_bf16
// pack two fp32 -> one u32 of 2 bf16 (lo = a, hi = b), single instruction
#define CVT_PK(dst, a, b) asm("v_cvt_pk_bf16_f32 %0, %1, %2" : "=v"(dst) : "v"(a), "v"(b))

__device__ __forceinline__ float silu_f(float x) {
    float e = __builtin_amdgcn_exp2f(x * -1.442695041f);   // exp(-x)
    return x * __builtin_amdgcn_rcpf(1.0f + e);
}
__device__ __forceinline__ float sigm_f(float x) {
    float e = __builtin_amdgcn_exp2f(x * -1.442695041f);
    return __builtin_amdgcn_rcpf(1.0f + e);
}

__device__ __forceinline__ short f2bf(float f) {   // RNE fp32 -> bf16 bits (pack path)
    unsigned u = __builtin_bit_cast(unsigned, f);
    u = (u + 0x7FFFu + ((u >> 16) & 1u)) >> 16;
    return (short)u;
}
__device__ __forceinline__ float bfhi(unsigned u) {      // hi bf16 of a u32 -> f32
    return __builtin_bit_cast(float, u & 0xFFFF0000u);
}
__device__ __forceinline__ float bflo(unsigned u) {      // lo bf16 of a u32 -> f32
    return __builtin_bit_cast(float, u << 16);
}

// ---------------------------------------------------------------------------
// Pack a [128 x ncols] fp32 weight into MFMA B-fragment order (bf16):
// frag (ct, kt): lane holds W[kt*32 + (lane>>4)*8 + j][ct*16 + (lane&15)], j=0..7
// ---------------------------------------------------------------------------
__global__ __launch_bounds__(256)
void k_pack(const float* __restrict__ W, short* __restrict__ out, int ncols)
{
    int idx = blockIdx.x * 256 + threadIdx.x;
    int lane = idx & 63, kt = (idx >> 6) & 3, ct = idx >> 8;
    if (ct * 16 >= ncols) return;
    int kg = lane >> 4, cl = lane & 15;
    bf16x8 v;
    #pragma unroll
    for (int j = 0; j < 8; ++j)
        v[j] = f2bf(W[(kt * 32 + kg * 8 + j) * ncols + ct * 16 + cl]);
    *(bf16x8*)(out + (size_t)idx * 8) = v;
}

// ---------------------------------------------------------------------------
// Kernel 1: per-node projections through the sender/receiver blocks of We1.
// ---------------------------------------------------------------------------
__global__ __launch_bounds__(128)
void k_proj(const float* __restrict__ feat, const float* __restrict__ We1,
            float* __restrict__ FsP, float* __restrict__ FrP)
{
    __shared__ float sF[128];
    int n = blockIdx.x, j = threadIdx.x;
    sF[j] = feat[n * 128 + j];
    __syncthreads();
    float a = 0.f, b = 0.f;
    #pragma unroll 8
    for (int k = 0; k < 128; ++k) {
        float f = sF[k];
        a = fmaf(f, We1[(8   + k) * 128 + j], a);
        b = fmaf(f, We1[(136 + k) * 128 + j], b);
    }
    FsP[n * 128 + j] = a;
    FrP[n * 128 + j] = b;
}

// ---------------------------------------------------------------------------
// streamed B-fragment loader (coalesced 16B/lane from packed layout, L2-hot)
// ---------------------------------------------------------------------------
__device__ __forceinline__ void loadB(const short* __restrict__ p,
                                      bf16x8 (&B)[2][4], int w, int lane)
{
    const bf16x8* p8 = (const bf16x8*)p;
    #pragma unroll
    for (int ctl = 0; ctl < 2; ++ctl)
        #pragma unroll
        for (int kt = 0; kt < 4; ++kt)
            B[ctl][kt] = p8[((w * 2 + ctl) * 4 + kt) * 64 + lane];
}

// 32x128 @ 128x128 core: A from swizzled bf16 LDS, B in VGPRs, silu(scale*x),
// bf16 (cvt_pk) scatter back to LDS. Per wave: cols [w*32, w*32+32).
template<bool KEEP>
__device__ __forceinline__ void gemm_core(const short* sIn_, short* sOut_,
                                          const bf16x8 (&B)[2][4],
                                          const int (&adrK)[4],
                                          const int (&wAdr)[2][4],
                                          float scale, f32x4 (&keep)[2][2])
{
    const char* sIn = (const char*)sIn_;
    char* sOut = (char*)sOut_;
    const f32x4 z = {0.f, 0.f, 0.f, 0.f};
    f32x4 acc[2][2] = {{z, z}, {z, z}};
    #pragma unroll
    for (int kt = 0; kt < 4; ++kt) {
        bf16x8 a0 = *(const bf16x8*)(sIn + adrK[kt]);
        bf16x8 a1 = *(const bf16x8*)(sIn + adrK[kt] + 4096);
        acc[0][0] = MFMA16(a0, B[0][kt], acc[0][0], 0, 0, 0);
        acc[0][1] = MFMA16(a0, B[1][kt], acc[0][1], 0, 0, 0);
        acc[1][0] = MFMA16(a1, B[0][kt], acc[1][0], 0, 0, 0);
        acc[1][1] = MFMA16(a1, B[1][kt], acc[1][1], 0, 0, 0);
    }
    #pragma unroll
    for (int rt = 0; rt < 2; ++rt)
        #pragma unroll
        for (int ctl = 0; ctl < 2; ++ctl) {
            float v0 = silu_f(acc[rt][ctl][0] * scale);
            float v1 = silu_f(acc[rt][ctl][1] * scale);
            float v2 = silu_f(acc[rt][ctl][2] * scale);
            float v3 = silu_f(acc[rt][ctl][3] * scale);
            if (KEEP) {
                keep[rt][ctl][0] = v0; keep[rt][ctl][1] = v1;
                keep[rt][ctl][2] = v2; keep[rt][ctl][3] = v3;
            }
            unsigned p01, p23;
            CVT_PK(p01, v0, v1);
            CVT_PK(p23, v2, v3);
            char* o = sOut + rt * 4096;
            *(short*)(o + wAdr[ctl][0]) = (short)(p01 & 0xFFFFu);
            *(short*)(o + wAdr[ctl][1]) = (short)(p01 >> 16);
            *(short*)(o + wAdr[ctl][2]) = (short)(p23 & 0xFFFFu);
            *(short*)(o + wAdr[ctl][3]) = (short)(p23 >> 16);
        }
}

// ---------------------------------------------------------------------------
// Kernel 2: one block per (sender, half); 8 chunks of 32 receivers.
// ---------------------------------------------------------------------------
__global__ __launch_bounds__(256, 3)
void k_edge(const float* __restrict__ pos,
            const float* __restrict__ We1,
            const float* __restrict__ Winf,
            const float* __restrict__ FsP,
            const float* __restrict__ FrP,
            const short* __restrict__ We2p,
            const short* __restrict__ Wx1p,
            const short* __restrict__ Wx2p,
            const short* __restrict__ Wtpp,
            float* __restrict__ MI2,
            float* __restrict__ VEC2)
{
    __shared__ __align__(16) short sX[CH * 128];   // activations ping (swizzled)
    __shared__ __align__(16) short sY[CH * 128];   // activations pong
    __shared__ __align__(16) float sLS[CH * NV * 4]; // (sh.xyz, len), v-slot swizzled
    __shared__ float sWinf[8 * 17];                // stride-17 (conflict-free)
    __shared__ float sPosS[24];
    __shared__ float sE[CH];
    __shared__ float sVp[4 * 24];

    const int bid = blockIdx.x;
    const int s = bid >> 1, half = bid & 1;
    const int t = threadIdx.x;
    const int lane = t & 63, w = t >> 6;
    const int rl = lane & 15, kg = lane >> 4;

    // ---- per-thread constant LDS byte addresses ----
    const int swz = (rl & 7) << 4;
    const int ktperm = (rl & 4) << 4;                 // swz bit 6
    const int baseRd = rl * 256 + ((kg * 16) ^ (swz & 0x30));
    int adrK[4];
    #pragma unroll
    for (int kt = 0; kt < 4; ++kt) adrK[kt] = baseRd + ((kt * 64) ^ ktperm);
    int wAdr[2][4];
    #pragma unroll
    for (int ctl = 0; ctl < 2; ++ctl)
        #pragma unroll
        for (int jj = 0; jj < 4; ++jj) {
            int r = kg * 4 + jj;
            wAdr[ctl][jj] = r * 256 + ((w * 64 + ctl * 32 + 2 * rl) ^ ((r & 7) << 4));
        }
    const int colg0 = w * 32 + rl, colg1 = colg0 + 16;
    const int er = t >> 3, eo = t & 7;
    const int eAdr0 = er * 256 + ((eo * 32)      ^ ((er & 7) << 4));
    const int eAdr1 = er * 256 + ((eo * 32 + 16) ^ ((er & 7) << 4));
    const int vv = w * 2 + (rl >> 3);                 // TP phase: fixed v per lane

    if (t < 128) sWinf[(t >> 4) * 17 + (t & 15)] = Winf[t];
    if (t < 24)  sPosS[t] = pos[s * 24 + t];

    // ---- pinned fragments: We2 (32 VGPR) + length-GEMM B (8 VGPR) ----
    bf16x8 Bwe2[2][4];
    loadB(We2p, Bwe2, w, lane);
    bf16x8 Blen[2];
    #pragma unroll
    for (int ctl = 0; ctl < 2; ++ctl) {
        int col = w * 32 + ctl * 16 + rl;
        bf16x8 b = {0, 0, 0, 0, 0, 0, 0, 0};
        if (kg == 0) {
            #pragma unroll
            for (int j = 0; j < 8; ++j) b[j] = f2bf(We1[j * 128 + col]);
        } else if (kg == 1) {
            b[0] = f2bf(FsP[s * 128 + col]);   // k=8 slot carries +FsP[s]
        }
        Blen[ctl] = b;
    }

    float miacc0 = 0.f, miacc1 = 0.f;
    float vax = 0.f, vay = 0.f, vaz = 0.f;
    __syncthreads();                                              // B0

    for (int c = 0; c < NCHH; ++c) {
        const int r0 = (half * NCHH + c) * CH;

        // ---- FrP prefetch in D-layout (16 scalar loads, L2-hot) ----
        float frv[2][2][4];
        #pragma unroll
        for (int rt = 0; rt < 2; ++rt)
            #pragma unroll
            for (int jj = 0; jj < 4; ++jj) {
                const float* fp = FrP + (size_t)(r0 + rt * 16 + kg * 4 + jj) * 128;
                frv[rt][0][jj] = fp[colg0];
                frv[rt][1][jj] = fp[colg1];
            }

        // ---- ph0: lengths + sh1 -> sLS ----
        {
            int r = t >> 3, v = t & 7;
            const float* pr = pos + (size_t)(r0 + r) * 24 + v * 3;
            float dx = sPosS[v * 3 + 0] - pr[0];
            float dy = sPosS[v * 3 + 1] - pr[1];
            float dz = sPosS[v * 3 + 2] - pr[2];
            float sq  = dx * dx + dy * dy + dz * dz;
            float len = sqrtf(fmaxf(sq, 1e-20f));   // r==s -> dx=0 -> sh1=0
            float inv = SQRT3 / len;
            f32x4 o; o[0] = dx * inv; o[1] = dy * inv; o[2] = dz * inv; o[3] = len;
            *(f32x4*)(sLS + (r * 8 + (v ^ (r & 7))) * 4) = o;
        }
        __syncthreads();                                          // B1

        // ---- prefetch Wx1 fragments (consumed 2 phases later) ----
        bf16x8 Bwx1[2][4];
        loadB(Wx1p, Bwx1, w, lane);

        // ---- length-GEMM via MFMA (K padded to 32; k=8 slot = +FsP) ----
        {
            bf16x8 aL0 = {0,0,0,0,0,0,0,0}, aL1 = {0,0,0,0,0,0,0,0};
            if (kg == 0) {
                const float* Lp = sLS + rl * 32;
                const float* Lq = sLS + (rl + 16) * 32;
                unsigned u0[4], u1[4];
                #pragma unroll
                for (int jp = 0; jp < 4; ++jp) {
                    CVT_PK(u0[jp], Lp[((2*jp)   ^ (rl & 7)) * 4 + 3],
                                   Lp[((2*jp+1) ^ (rl & 7)) * 4 + 3]);
                    CVT_PK(u1[jp], Lq[((2*jp)   ^ (rl & 7)) * 4 + 3],
                                   Lq[((2*jp+1) ^ (rl & 7)) * 4 + 3]);
                }
                uint4 v0 = {u0[0], u0[1], u0[2], u0[3]};
                uint4 v1 = {u1[0], u1[1], u1[2], u1[3]};
                aL0 = __builtin_bit_cast(bf16x8, v0);
                aL1 = __builtin_bit_cast(bf16x8, v1);
            } else if (kg == 1) {
                aL0[0] = (short)0x3F80;  aL1[0] = (short)0x3F80;   // 1.0bf
            }
            const f32x4 z = {0.f, 0.f, 0.f, 0.f};
            f32x4 aP[2][2];
            aP[0][0] = MFMA16(aL0, Blen[0], z, 0, 0, 0);
            aP[0][1] = MFMA16(aL0, Blen[1], z, 0, 0, 0);
            aP[1][0] = MFMA16(aL1, Blen[0], z, 0, 0, 0);
            aP[1][1] = MFMA16(aL1, Blen[1], z, 0, 0, 0);
            char* sXc = (char*)sX;
            #pragma unroll
            for (int rt = 0; rt < 2; ++rt)
                #pragma unroll
                for (int ctl = 0; ctl < 2; ++ctl) {
                    float v0 = silu_f((aP[rt][ctl][0] + frv[rt][ctl][0]) * C1);
                    float v1 = silu_f((aP[rt][ctl][1] + frv[rt][ctl][1]) * C1);
                    float v2 = silu_f((aP[rt][ctl][2] + frv[rt][ctl][2]) * C1);
                    float v3 = silu_f((aP[rt][ctl][3] + frv[rt][ctl][3]) * C1);
                    unsigned p01, p23;
                    CVT_PK(p01, v0, v1);
                    CVT_PK(p23, v2, v3);
                    char* o = sXc + rt * 4096;
                    *(short*)(o + wAdr[ctl][0]) = (short)(p01 & 0xFFFFu);
                    *(short*)(o + wAdr[ctl][1]) = (short)(p01 >> 16);
                    *(short*)(o + wAdr[ctl][2]) = (short)(p23 & 0xFFFFu);
                    *(short*)(o + wAdr[ctl][3]) = (short)(p23 >> 16);
                }
        }
        __syncthreads();                                          // B2

        // ---- prefetch Wx2 (consumed 2 phases later) ----
        bf16x8 Bwx2[2][4];
        loadB(Wx2p, Bwx2, w, lane);

        // ---- m_ij = silu(C2 * a1 @ We2) -> sY ; keep fp32 copies ----
        f32x4 keepM[2][2];
        gemm_core<true>(sX, sY, Bwe2, adrK, wAdr, C2, keepM);
        __syncthreads();                                          // B3

        // ---- prefetch Wtp (consumed 3 phases later) ----
        bf16x8 Btp[4];
        {
            const bf16x8* p8 = (const bf16x8*)Wtpp;
            #pragma unroll
            for (int kt = 0; kt < 4; ++kt) Btp[kt] = p8[(w * 4 + kt) * 64 + lane];
        }

        // ---- e[r] = sigmoid(C2 * m_ij . Winf)  (in-wave shfl reduce) ----
        {
            const char* sYc = (const char*)sY;
            uint4 m0 = *(const uint4*)(sYc + eAdr0);
            uint4 m1 = *(const uint4*)(sYc + eAdr1);
            const unsigned mu[8] = {m0.x, m0.y, m0.z, m0.w, m1.x, m1.y, m1.z, m1.w};
            float d = 0.f;
            #pragma unroll
            for (int q = 0; q < 8; ++q) {
                d = fmaf(bflo(mu[q]), sWinf[eo * 17 + 2 * q],     d);
                d = fmaf(bfhi(mu[q]), sWinf[eo * 17 + 2 * q + 1], d);
            }
            d += __shfl_xor(d, 1); d += __shfl_xor(d, 2); d += __shfl_xor(d, 4);
            if (eo == 0) sE[er] = (r0 + er == s) ? 0.f : sigm_f(d * C2);
        }
        __syncthreads();                                          // B5

        // ---- m_i accumulation from registers ----
        #pragma unroll
        for (int rt = 0; rt < 2; ++rt)
            #pragma unroll
            for (int jj = 0; jj < 4; ++jj) {
                float e = sE[rt * 16 + kg * 4 + jj];
                miacc0 = fmaf(keepM[rt][0][jj], e, miacc0);
                miacc1 = fmaf(keepM[rt][1][jj], e, miacc1);
            }

        // ---- phi_x layer 1 (prefetched Wx1) ----
        gemm_core<false>(sY, sX, Bwx1, adrK, wAdr, C2, keepM);
        __syncthreads();                                          // B6
        // ---- phi_x layer 2 (prefetched Wx2) ----
        gemm_core<false>(sX, sY, Bwx2, adrK, wAdr, C2, keepM);
        __syncthreads();                                          // B7

        // ---- TP gemm (prefetched Wtp, per-wave 16 cols) + vec acc from regs ----
        {
            const f32x4 z = {0.f, 0.f, 0.f, 0.f};
            f32x4 acc0 = z, acc1 = z;
            const char* sYc = (const char*)sY;
            #pragma unroll
            for (int kt = 0; kt < 4; ++kt) {
                bf16x8 a0 = *(const bf16x8*)(sYc + adrK[kt]);
                bf16x8 a1 = *(const bf16x8*)(sYc + adrK[kt] + 4096);
                acc0 = MFMA16(a0, Btp[kt], acc0, 0, 0, 0);
                acc1 = MFMA16(a1, Btp[kt], acc1, 0, 0, 0);
            }
            #pragma unroll
            for (int rt = 0; rt < 2; ++rt)
                #pragma unroll
                for (int jj = 0; jj < 4; ++jj) {
                    int row = rt * 16 + kg * 4 + jj;
                    const f32x4 sh = *(const f32x4*)(sLS + (row * 8 + (vv ^ (row & 7))) * 4);
                    float g = rt ? acc1[jj] : acc0[jj];
                    vax = fmaf(g, sh[0], vax);
                    vay = fmaf(g, sh[1], vay);
                    vaz = fmaf(g, sh[2], vaz);
                }
        }
        __syncthreads();                                          // B8
    }

    // ---- epilogue: m_i reduce over row-groups ----
    miacc0 += __shfl_xor(miacc0, 16); miacc0 += __shfl_xor(miacc0, 32);
    miacc1 += __shfl_xor(miacc1, 16); miacc1 += __shfl_xor(miacc1, 32);
    if (lane < 16) {
        float* mo = MI2 + (size_t)(half * NN + s) * 128;
        mo[w * 32 + lane]      = miacc0;
        mo[w * 32 + 16 + lane] = miacc1;
    }
    // ---- vec reduce: over rl&8 (v-pair) then kg groups ----
    vax += __shfl_xor(vax, 8);  vay += __shfl_xor(vay, 8);  vaz += __shfl_xor(vaz, 8);
    vax += __shfl_xor(vax, 16); vay += __shfl_xor(vay, 16); vaz += __shfl_xor(vaz, 16);
    vax += __shfl_xor(vax, 32); vay += __shfl_xor(vay, 32); vaz += __shfl_xor(vaz, 32);
    if ((lane & 56) == 0) {     // lanes 0..7: wv = lane
        float* vp = sVp + w * 24 + lane * 3;
        vp[0] = vax; vp[1] = vay; vp[2] = vaz;
    }
    __syncthreads();
    if (t < 24) {
        float sum = sVp[t] + sVp[24 + t] + sVp[48 + t] + sVp[72 + t];
        VEC2[(size_t)(half * NN + s) * 24 + t] = sum * (1.0f / 32.0f);
    }
}

// ---------------------------------------------------------------------------
// Kernel 3: per-node h-MLP + residual + position update (sums the 2 halves).
// ---------------------------------------------------------------------------
__global__ __launch_bounds__(128)
void k_node(const float* __restrict__ pos, const float* __restrict__ feat,
            const float* __restrict__ Wh1, const float* __restrict__ Wh2,
            const float* __restrict__ Wh3,
            const float* __restrict__ MI2, const float* __restrict__ VEC2,
            float* __restrict__ outPos, float* __restrict__ outFeat)
{
    __shared__ float sMi[128], sF[128], sH[128];
    int n = blockIdx.x, j = threadIdx.x;
    sMi[j] = MI2[n * 128 + j] + MI2[NN * 128 + n * 128 + j];
    sF[j]  = feat[n * 128 + j];
    __syncthreads();
    float a = 0.f;
    #pragma unroll 8
    for (int k = 0; k < 128; ++k) a = fmaf(sMi[k], Wh1[k * 128 + j], a);
    #pragma unroll 8
    for (int k = 0; k < 128; ++k) a = fmaf(sF[k], Wh1[(128 + k) * 128 + j], a);
    a = silu_f(a * 0.0625f);            // 1/sqrt(256)
    sH[j] = a;
    __syncthreads();
    float b = 0.f;
    #pragma unroll 8
    for (int k = 0; k < 128; ++k) b = fmaf(sH[k], Wh2[k * 128 + j], b);
    b = silu_f(b * C2);
    sMi[j] = b;
    __syncthreads();
    float cc = 0.f;
    #pragma unroll 8
    for (int k = 0; k < 128; ++k) cc = fmaf(sMi[k], Wh3[k * 128 + j], cc);
    outFeat[n * 128 + j] = cc * C2 + sF[j];
    if (j < 24) outPos[n * 24 + j] = pos[n * 24 + j]
                                   + VEC2[n * 24 + j] + VEC2[NN * 24 + n * 24 + j];
}

// ---------------------------------------------------------------------------
extern "C" void kernel_launch(void* const* d_in, const int* in_sizes, int n_in,
                              void* d_out, int out_size, void* d_ws, size_t ws_size,
                              hipStream_t stream) {
    const float* pos  = (const float*)d_in[0];
    const float* feat = (const float*)d_in[1];
    const float* We1  = (const float*)d_in[2];
    const float* We2  = (const float*)d_in[3];
    const float* Wx1  = (const float*)d_in[4];
    const float* Wx2  = (const float*)d_in[5];
    const float* Winf = (const float*)d_in[6];
    const float* Wtp  = (const float*)d_in[7];
    const float* Wh1  = (const float*)d_in[8];
    const float* Wh2  = (const float*)d_in[9];
    const float* Wh3  = (const float*)d_in[10];

    float* outPos  = (float*)d_out;              // [512*8*3]
    float* outFeat = (float*)d_out + NN * 24;    // [512*128]

    float* ws   = (float*)d_ws;
    float* FsP  = ws;                   // 65536 floats
    float* FrP  = ws + 65536;           // 65536
    float* MI2  = ws + 131072;          // 2*65536
    float* VEC2 = ws + 262144;          // 2*12288
    short* wpack = (short*)(ws + 286720);
    short* We2p = wpack;                // 16384 shorts
    short* Wx1p = wpack + 16384;        // 16384
    short* Wx2p = wpack + 32768;        // 16384
    short* Wtpp = wpack + 49152;        // 8192   (total ws ~1.21 MB)

    k_pack<<<dim3(8), dim3(256), 0, stream>>>(We2, We2p, 128);
    k_pack<<<dim3(8), dim3(256), 0, stream>>>(Wx1, Wx1p, 128);
    k_pack<<<dim3(8), dim3(256), 0, stream>>>(Wx2, Wx2p, 128);
    k_pack<<<dim3(4), dim3(256), 0, stream>>>(Wtp, Wtpp, 64);
    k_proj<<<dim3(NN), dim3(128), 0, stream>>>(feat, We1, FsP, FrP);
    k_edge<<<dim3(2 * NN), dim3(256), 0, stream>>>(pos, We1, Winf, FsP, FrP,
                                                   We2p, Wx1p, Wx2p, Wtpp, MI2, VEC2);
    k_node<<<dim3(NN), dim3(128), 0, stream>>>(pos, feat, Wh1, Wh2, Wh3, MI2, VEC2,
                                               outPos, outFeat);
}